// Round 6
// baseline (243.600 us; speedup 1.0000x reference)
//
#include <hip/hip_runtime.h>
#include <math.h>

#define N_USERS 1000000
#define N_ITEMS 100000
#define EMB 16
#define OUTD 16
#define NH 4
#define HID 32
#define BB 8192
#define SS 200
#define LL 50
#define NSUPP 50000

#define SLICE_ROWS 1536
#define NP 33                               // ceil(50000/1536)
#define TBL_ROWS (NP * SLICE_ROWS)          // 50688 (padded)
#define SLICE_BYTES (SLICE_ROWS * EMB * 2)  // 49152
#define GBB 32                              // b's per attn block

typedef float v4f __attribute__((ext_vector_type(4)));
typedef _Float16 h2 __attribute__((ext_vector_type(2)));
typedef _Float16 h8 __attribute__((ext_vector_type(8)));

// within-wave DS ordering fence (drain LDS ops; rule: follow inline-asm
// lgkmcnt with a sched_barrier so the compiler can't hoist past it)
#define WAVE_SYNC() do { asm volatile("s_waitcnt lgkmcnt(0)" ::: "memory"); \
                         __builtin_amdgcn_sched_barrier(0); } while (0)

// ---------------------------------------------------------------------------
// Kernel 1 (prep):
//  blocks [0, 3125):        fp16 user table: tbl[n] = (fp16) user_emb[supp[n]]
//  blocks [3125, 3125+2048): user_init -> q -> q~ (q~_e = sum_o wk[h][e][o] q_o)
//  block  3125+2048:         Wkv[h] = wk[h] @ wv[h]  (16x16 per head, fp32)
// Algebra: score = u . q~ ; ctx = (sum_s w u) @ wk ; gat = (cu @ Wkv)/l.
// K is never materialized; the gathered table is 1.6 MB total for all heads.
// ---------------------------------------------------------------------------
__global__ __launch_bounds__(256) void prep_kernel(
    const float* __restrict__ user_emb,
    const int*   __restrict__ supp_users,
    const float* __restrict__ wk,
    const float* __restrict__ wq,
    const float* __restrict__ wv,
    const float* __restrict__ item_emb,
    const int*   __restrict__ history,
    const int*   __restrict__ history_len,
    _Float16*    __restrict__ tbl,
    _Float16*    __restrict__ qtbuf,
    float*       __restrict__ Wkv)
{
    __shared__ float s_ui[4][EMB];
    __shared__ float s_wq[NH * EMB * OUTD];
    __shared__ float s_wk[NH * EMB * OUTD];
    __shared__ float s_q[4][NH * OUTD];

    int t = threadIdx.x;
    if (blockIdx.x < NSUPP / 16) {
        // ---- fp16 user table (16 rows / block) ----
        int n0 = blockIdx.x * 16;
        int ul = t >> 4, e = t & 15;
        int row = supp_users[n0 + ul];
        tbl[(size_t)(n0 + ul) * EMB + e] =
            (_Float16)user_emb[(size_t)row * EMB + e];
    } else if (blockIdx.x < NSUPP / 16 + BB / 4) {
        // ---- user_init -> q -> q~ ----
        for (int i = t; i < NH * EMB * OUTD; i += 256) {
            s_wq[i] = wq[i];
            s_wk[i] = wk[i];
        }
        int g    = t >> 6;
        int lane = t & 63;
        int l4   = lane >> 4;
        int e    = lane & 15;
        int b    = (blockIdx.x - NSUPP / 16) * 4 + g;

        float sum = 0.f;
        for (int l = l4; l < LL; l += 4) {
            int it = __builtin_nontemporal_load(history + (size_t)b * LL + l);
            sum += item_emb[(size_t)it * EMB + e];
        }
        sum += __shfl_xor(sum, 16);
        sum += __shfl_xor(sum, 32);
        if (lane < EMB) s_ui[g][lane] = sum / (float)history_len[b];
        __syncthreads();

        int h = (t >> 4) & 3;
        int o = t & 15;
        float acc = 0.f;
#pragma unroll
        for (int ee = 0; ee < EMB; ++ee)
            acc += s_ui[g][ee] * s_wq[(h * EMB + ee) * OUTD + o];
        s_q[g][h * OUTD + o] = acc;
        __syncthreads();

        // q~_e = sum_o wk[h][e][o] * q_o
        float qt = 0.f;
#pragma unroll
        for (int oo = 0; oo < OUTD; ++oo)
            qt += s_wk[(h * EMB + o) * OUTD + oo] * s_q[g][h * OUTD + oo];
        qtbuf[((size_t)b * NH + h) * EMB + o] = (_Float16)qt;
    } else {
        // ---- Wkv[h][e][p] = sum_o wk[h][e][o] * wv[h][o][p] ----
        for (int i = t; i < NH * EMB * OUTD; i += 256) {
            int h = i >> 8, e = (i >> 4) & 15, p = i & 15;
            float a = 0.f;
#pragma unroll
            for (int o = 0; o < OUTD; ++o)
                a += wk[(h * EMB + e) * OUTD + o] * wv[(h * OUTD + o) * OUTD + p];
            Wkv[i] = a;
        }
    }
}

// ---------------------------------------------------------------------------
// Kernel 2: LDS-streamed attention, grid = 256 blocks (1 per CU).
// Block = 32 b x 4 heads = 128 (h,b); 8 waves x 16 quads; quad owns one (h,b).
// R5 fixes (VALUBusy 29%, 70% stall):
//  (1) bucketing prefix via 6-step __shfl_up scan (was serial lane-0 loop,
//      ~8 us of dead time);
//  (2) inner loop has a wave-uniform trip count (shfl-max over quads) and a
//      2-deep software pipeline: load list-idx for i+2, rows for i+1,
//      compute i -- LDS latency overlaps compute instead of serializing;
//  (3) no per-iteration ballot.
// Per-sample state (l, cu[16]) stays in lane registers; quad-reduced at the
// end into gat = (cu @ Wkv[h]) / l.
// ---------------------------------------------------------------------------
__global__ __launch_bounds__(512, 1) void attn_kernel(
    const _Float16* __restrict__ tbl,
    const _Float16* __restrict__ qtbuf,
    const int*   __restrict__ sample_index,
    const float* __restrict__ Wkv,
    float*       __restrict__ gat)
{
    __shared__ __align__(16) _Float16 s_slice[2][SLICE_ROWS * EMB]; // 96 KB
    __shared__ unsigned short s_list[128 * SS];                     // 51.2 KB
    __shared__ unsigned short s_ofs[128][NP + 1];                   // 8.7 KB
    __shared__ unsigned int   s_hist[8][40];                        // 1.3 KB

    int tid  = threadIdx.x;
    int wave = tid >> 6;
    int lane = tid & 63;
    int g    = lane >> 2;
    int qt   = lane & 3;
    int hb   = wave * 16 + g;          // this quad's (h,b): 0..127
    int h    = hb & 3;
    int bl   = hb >> 2;
    int bfull = blockIdx.x * GBB + bl;

    // ---- issue slice-0 loads (in flight during bucketing) ----
    v4f stg[6];
#pragma unroll
    for (int i = 0; i < 6; ++i)
        stg[i] = *(const v4f*)((const char*)tbl + (size_t)i * 8192 + (size_t)tid * 16);

    // ---- phase 0: per-wave counting-bucket of its 16 lists ----
    for (int bs = 0; bs < 16; ++bs) {
        int hbs = wave * 16 + bs;
        int hs = hbs & 3, bls = hbs >> 2;
        const int* si = sample_index + ((size_t)hs * BB + (blockIdx.x * GBB + bls)) * SS;
        int v0 = __builtin_nontemporal_load(si + lane);
        int v1 = __builtin_nontemporal_load(si + lane + 64);
        int v2 = __builtin_nontemporal_load(si + lane + 128);
        int v3 = (lane < SS - 192) ? __builtin_nontemporal_load(si + lane + 192) : -1;

        if (lane < NP) s_hist[wave][lane] = 0;
        WAVE_SYNC();
        // bucket id: v/1536 = (v>>9)/3, /3 via *21846>>16 (exact for n<=98301)
        int b0 = ((v0 >> 9) * 21846) >> 16;
        int b1 = ((v1 >> 9) * 21846) >> 16;
        int b2 = ((v2 >> 9) * 21846) >> 16;
        int b3 = (v3 >= 0) ? (((v3 >> 9) * 21846) >> 16) : 0;
        atomicAdd(&s_hist[wave][b0], 1u);
        atomicAdd(&s_hist[wave][b1], 1u);
        atomicAdd(&s_hist[wave][b2], 1u);
        if (v3 >= 0) atomicAdd(&s_hist[wave][b3], 1u);
        WAVE_SYNC();
        // exclusive prefix via shfl scan (was: serial lane-0 loop)
        unsigned c = (lane < NP) ? s_hist[wave][lane] : 0;
        unsigned sc = c;
#pragma unroll
        for (int d = 1; d < 64; d <<= 1) {
            unsigned tu = (unsigned)__shfl_up((int)sc, d, 64);
            if (lane >= d) sc += tu;
        }
        unsigned excl = sc - c;
        if (lane < NP) {
            s_hist[wave][lane] = excl;
            s_ofs[hbs][lane] = (unsigned short)excl;
        }
        if (lane == NP) s_ofs[hbs][NP] = (unsigned short)SS;
        WAVE_SYNC();
        unsigned p0 = atomicAdd(&s_hist[wave][b0], 1u);
        s_list[hbs * SS + p0] = (unsigned short)v0;
        unsigned p1 = atomicAdd(&s_hist[wave][b1], 1u);
        s_list[hbs * SS + p1] = (unsigned short)v1;
        unsigned p2 = atomicAdd(&s_hist[wave][b2], 1u);
        s_list[hbs * SS + p2] = (unsigned short)v2;
        if (v3 >= 0) {
            unsigned p3 = atomicAdd(&s_hist[wave][b3], 1u);
            s_list[hbs * SS + p3] = (unsigned short)v3;
        }
        WAVE_SYNC();
    }

    // ---- q~ for this quad (16 fp16 = 2 x h8, all 4 lanes hold a copy) ----
    const h8* qtp = (const h8*)(qtbuf + ((size_t)bfull * NH + h) * EMB);
    h8 qA = qtp[0], qB = qtp[1];
    h2 tq0 = __builtin_shufflevector(qA, qA, 0, 1);
    h2 tq1 = __builtin_shufflevector(qA, qA, 2, 3);
    h2 tq2 = __builtin_shufflevector(qA, qA, 4, 5);
    h2 tq3 = __builtin_shufflevector(qA, qA, 6, 7);
    h2 tq4 = __builtin_shufflevector(qB, qB, 0, 1);
    h2 tq5 = __builtin_shufflevector(qB, qB, 2, 3);
    h2 tq6 = __builtin_shufflevector(qB, qB, 4, 5);
    h2 tq7 = __builtin_shufflevector(qB, qB, 6, 7);

    // publish slice 0 (bucketing also complete -> one barrier covers both)
#pragma unroll
    for (int i = 0; i < 6; ++i)
        *(v4f*)((char*)&s_slice[0][0] + (size_t)i * 8192 + (size_t)tid * 16) = stg[i];
    __syncthreads();

    // ---- main loop over 33 slices ----
    float l = 0.f;
    float cu[16];
#pragma unroll
    for (int j = 0; j < 16; ++j) cu[j] = 0.f;
    int base = 0;

    for (int p = 0; p < NP; ++p) {
        if (p + 1 < NP) {                      // issue next slice (reg-staged)
            size_t sb = (size_t)(p + 1) * SLICE_BYTES;
#pragma unroll
            for (int i = 0; i < 6; ++i)
                stg[i] = *(const v4f*)((const char*)tbl + sb + (size_t)i * 8192
                                        + (size_t)tid * 16);
        }
        const h8* sl = (const h8*)&s_slice[p & 1][0];
        int pbase = p * SLICE_ROWS;
        int cnt = (int)s_ofs[hb][p + 1] - base;
        // wave-uniform trip count = max over the wave's 16 quads
        int mx = (cnt + 3) >> 2;
        mx = max(mx, __shfl_xor(mx, 4));
        mx = max(mx, __shfl_xor(mx, 8));
        mx = max(mx, __shfl_xor(mx, 16));
        mx = max(mx, __shfl_xor(mx, 32));
        const int lbase = hb * SS + base;

        if (mx > 0) {
            // 2-deep pipeline: idx for i+2, rows for i+1, compute i
            int offA = qt;
            bool vA  = offA < cnt;
            int idxA = (int)s_list[lbase + (vA ? offA : 0)];
            int offB = qt + 4;
            bool vB  = offB < cnt;
            int idxB = (int)s_list[lbase + (vB ? offB : 0)];
            int rlA  = vA ? idxA - pbase : 0;
            h8 uA0 = sl[rlA * 2];
            h8 uA1 = sl[rlA * 2 + 1];
            for (int it = 0; it < mx; ++it) {
                int rlB = vB ? idxB - pbase : 0;      // rows for stage B
                h8 uB0 = sl[rlB * 2];
                h8 uB1 = sl[rlB * 2 + 1];
                int offC = offB + 4;                  // idx for stage C
                bool vC  = offC < cnt;
                int idxC = (int)s_list[lbase + (vC ? offC : 0)];
                // compute stage A (two parallel fdot2 chains halve latency)
                h2 a0 = __builtin_shufflevector(uA0, uA0, 0, 1);
                h2 a1 = __builtin_shufflevector(uA0, uA0, 2, 3);
                h2 a2 = __builtin_shufflevector(uA0, uA0, 4, 5);
                h2 a3 = __builtin_shufflevector(uA0, uA0, 6, 7);
                h2 a4 = __builtin_shufflevector(uA1, uA1, 0, 1);
                h2 a5 = __builtin_shufflevector(uA1, uA1, 2, 3);
                h2 a6 = __builtin_shufflevector(uA1, uA1, 4, 5);
                h2 a7 = __builtin_shufflevector(uA1, uA1, 6, 7);
                float sx = __builtin_amdgcn_fdot2(a0, tq0,
                           __builtin_amdgcn_fdot2(a1, tq1,
                           __builtin_amdgcn_fdot2(a2, tq2,
                           __builtin_amdgcn_fdot2(a3, tq3, 0.f, false),
                           false), false), false);
                float sy = __builtin_amdgcn_fdot2(a4, tq4,
                           __builtin_amdgcn_fdot2(a5, tq5,
                           __builtin_amdgcn_fdot2(a6, tq6,
                           __builtin_amdgcn_fdot2(a7, tq7, 0.f, false),
                           false), false), false);
                float w = vA ? __expf(sx + sy) : 0.f;  // no-max softmax
                l += w;
#pragma unroll
                for (int j = 0; j < 8; ++j) cu[j]     += w * (float)uA0[j];
#pragma unroll
                for (int j = 0; j < 8; ++j) cu[8 + j] += w * (float)uA1[j];
                // rotate
                offA = offB; vA = vB; uA0 = uB0; uA1 = uB1;
                offB = offC; vB = vC; idxB = idxC;
            }
        }
        base += cnt;
        __syncthreads();                        // all reads of s_slice[p&1] done
        if (p + 1 < NP) {
#pragma unroll
            for (int i = 0; i < 6; ++i)
                *(v4f*)((char*)&s_slice[(p + 1) & 1][0] + (size_t)i * 8192
                        + (size_t)tid * 16) = stg[i];
        }
        __syncthreads();                        // next slice visible
    }

    // ---- quad reduce + gat = (cu @ Wkv[h]) / l ----
    l += __shfl_xor(l, 1);
    l += __shfl_xor(l, 2);
#pragma unroll
    for (int j = 0; j < 16; ++j) {
        cu[j] += __shfl_xor(cu[j], 1);
        cu[j] += __shfl_xor(cu[j], 2);
    }
    float inv = 1.f / l;
    v4f acc = {0.f, 0.f, 0.f, 0.f};
#pragma unroll
    for (int e = 0; e < EMB; ++e)
        acc += cu[e] * *(const v4f*)(Wkv + ((size_t)(h * EMB + e) * OUTD) + qt * 4);
    acc *= inv;
    *(v4f*)(gat + (size_t)bfull * (NH * OUTD) + h * OUTD + qt * 4) = acc;
}

// ---------------------------------------------------------------------------
// Kernel 3: epilogue per b (4 b per 256-thread block, one wave per b).
// ---------------------------------------------------------------------------
__global__ __launch_bounds__(256) void epilogue_kernel(
    const float* __restrict__ gat,
    const float* __restrict__ item_emb,
    const float* __restrict__ w_out,
    const float* __restrict__ l1_w, const float* __restrict__ l1_b,
    const float* __restrict__ l2_w, const float* __restrict__ l2_b,
    const float* __restrict__ l3_w, const float* __restrict__ l3_b,
    const float* __restrict__ user_bias, const float* __restrict__ item_bias,
    const int*   __restrict__ x,
    float*       __restrict__ out)
{
    int t    = threadIdx.x;
    int g    = t >> 6;
    int lane = t & 63;
    int b    = blockIdx.x * 4 + g;

    __shared__ float s_gat[4][NH * OUTD];
    __shared__ float s_ue[4][OUTD];
    __shared__ float s_ie[4][EMB];
    __shared__ float s_x1[4][HID];
    __shared__ float s_x2[4][HID / 2];

    int uid = x[(size_t)b * 2 + 0];
    int iid = x[(size_t)b * 2 + 1];

    s_gat[g][lane] = gat[(size_t)b * (NH * OUTD) + lane];
    if (lane < EMB) s_ie[g][lane] = item_emb[(size_t)iid * EMB + lane];
    __syncthreads();

    if (lane < OUTD) {
        float acc = 0.f;
#pragma unroll
        for (int j = 0; j < NH * OUTD; ++j) acc += s_gat[g][j] * w_out[j * OUTD + lane];
        s_ue[g][lane] = acc;
    }
    __syncthreads();

    if (lane < HID) {
        float acc = l1_b[lane];
#pragma unroll
        for (int i = 0; i < EMB; ++i) {
            float ue = s_ue[g][i], ie = s_ie[g][i];
            acc += ue * l1_w[i * HID + lane]
                 + ie * l1_w[(EMB + i) * HID + lane]
                 + ue * ie * l1_w[(2 * EMB + i) * HID + lane];
        }
        s_x1[g][lane] = tanhf(acc);
    }
    __syncthreads();

    if (lane < HID / 2) {
        float acc = l2_b[lane];
#pragma unroll
        for (int j = 0; j < HID; ++j) acc += s_x1[g][j] * l2_w[j * (HID / 2) + lane];
        s_x2[g][lane] = tanhf(acc);
    }
    __syncthreads();

    if (lane == 0) {
        float x3 = l3_b[0];
#pragma unroll
        for (int j = 0; j < HID / 2; ++j) x3 += s_x2[g][j] * l3_w[j];
        float ratings = 0.f;
#pragma unroll
        for (int o = 0; o < OUTD; ++o) ratings += s_ue[g][o] * s_ie[g][o];
        out[b] = 0.5f * (ratings + x3) + user_bias[uid] + item_bias[iid];
    }
}

// ---------------------------------------------------------------------------
extern "C" void kernel_launch(void* const* d_in, const int* in_sizes, int n_in,
                              void* d_out, int out_size, void* d_ws, size_t ws_size,
                              hipStream_t stream) {
    const float* user_embedding = (const float*)d_in[0];
    const float* item_embedding = (const float*)d_in[1];
    const float* wq             = (const float*)d_in[2];
    const float* wk             = (const float*)d_in[3];
    const float* wv             = (const float*)d_in[4];
    const float* w_out          = (const float*)d_in[5];
    const float* l1_w           = (const float*)d_in[6];
    const float* l1_b           = (const float*)d_in[7];
    const float* l2_w           = (const float*)d_in[8];
    const float* l2_b           = (const float*)d_in[9];
    const float* l3_w           = (const float*)d_in[10];
    const float* l3_b           = (const float*)d_in[11];
    const float* user_bias      = (const float*)d_in[12];
    const float* item_bias      = (const float*)d_in[13];
    const int*   x              = (const int*)d_in[14];
    const int*   history        = (const int*)d_in[15];
    const int*   history_len    = (const int*)d_in[16];
    const int*   supp_users     = (const int*)d_in[17];
    const int*   sample_index   = (const int*)d_in[18];
    float* out = (float*)d_out;

    char* ws = (char*)d_ws;
    _Float16* tbl = (_Float16*)ws;                       // 50688*32 B = 1.62 MB
    ws += (size_t)TBL_ROWS * EMB * sizeof(_Float16);
    _Float16* qtbuf = (_Float16*)ws;                     // 1 MB
    ws += (size_t)BB * NH * EMB * sizeof(_Float16);
    float* gat = (float*)ws;                             // 2 MB
    ws += (size_t)BB * NH * OUTD * sizeof(float);
    float* Wkv = (float*)ws;                             // 4 KB

    prep_kernel<<<NSUPP / 16 + BB / 4 + 1, 256, 0, stream>>>(
        user_embedding, supp_users, wk, wq, wv,
        item_embedding, history, history_len, tbl, qtbuf, Wkv);
    attn_kernel<<<BB / GBB, 512, 0, stream>>>(tbl, qtbuf, sample_index, Wkv, gat);
    epilogue_kernel<<<BB / 4, 256, 0, stream>>>(
        gat, item_embedding, w_out, l1_w, l1_b, l2_w, l2_b, l3_w, l3_b,
        user_bias, item_bias, x, out);
}

// Round 7
// 200.408 us; speedup vs baseline: 1.2155x; 1.2155x over previous
//
#include <hip/hip_runtime.h>
#include <math.h>

#define N_USERS 1000000
#define N_ITEMS 100000
#define EMB 16
#define OUTD 16
#define NH 4
#define HID 32
#define BB 8192
#define SS 200
#define LL 50
#define NSUPP 50000

typedef float v4f __attribute__((ext_vector_type(4)));
typedef _Float16 h2 __attribute__((ext_vector_type(2)));
typedef _Float16 h4 __attribute__((ext_vector_type(4)));

// within-wave LDS ordering fence (lockstep wave; drain DS ops; keep the
// sched_barrier so the compiler can't hoist dependent ops above the wait)
#define WAVE_SYNC() do { asm volatile("s_waitcnt lgkmcnt(0)" ::: "memory"); \
                         __builtin_amdgcn_sched_barrier(0); } while (0)

// ---------------------------------------------------------------------------
// Kernel 1 (prep) — unchanged from R5 (best measured non-attn path):
//  blocks [0, 3125):         fp16 user table: tbl[n] = (fp16) user_emb[supp[n]]
//  blocks [3125, 3125+2048): user_init -> q -> q~ (q~_e = sum_o wk[h][e][o] q_o)
//  block  3125+2048:         Wkv[h] = wk[h] @ wv[h]  (16x16 per head, fp32)
// Algebra: score = u . q~ ; ctx = sum_s w u ; gat = (ctx @ Wkv)/l.
// K is never materialized; the gathered table is 1.6 MB for ALL heads ->
// fits every XCD's 4 MB L2 (no head pinning needed; fusion is safe).
// ---------------------------------------------------------------------------
__global__ __launch_bounds__(256) void prep_kernel(
    const float* __restrict__ user_emb,
    const int*   __restrict__ supp_users,
    const float* __restrict__ wk,
    const float* __restrict__ wq,
    const float* __restrict__ wv,
    const float* __restrict__ item_emb,
    const int*   __restrict__ history,
    const int*   __restrict__ history_len,
    _Float16*    __restrict__ tbl,
    _Float16*    __restrict__ qtbuf,
    float*       __restrict__ Wkv)
{
    __shared__ float s_ui[4][EMB];
    __shared__ float s_wq[NH * EMB * OUTD];
    __shared__ float s_wk[NH * EMB * OUTD];
    __shared__ float s_q[4][NH * OUTD];

    int t = threadIdx.x;
    if (blockIdx.x < NSUPP / 16) {
        // ---- fp16 user table (16 rows / block) ----
        int n0 = blockIdx.x * 16;
        int ul = t >> 4, e = t & 15;
        int row = supp_users[n0 + ul];
        tbl[(size_t)(n0 + ul) * EMB + e] =
            (_Float16)user_emb[(size_t)row * EMB + e];
    } else if (blockIdx.x < NSUPP / 16 + BB / 4) {
        // ---- user_init -> q -> q~ ----
        for (int i = t; i < NH * EMB * OUTD; i += 256) {
            s_wq[i] = wq[i];
            s_wk[i] = wk[i];
        }
        int g    = t >> 6;
        int lane = t & 63;
        int l4   = lane >> 4;
        int e    = lane & 15;
        int b    = (blockIdx.x - NSUPP / 16) * 4 + g;

        float sum = 0.f;
        for (int l = l4; l < LL; l += 4) {
            int it = __builtin_nontemporal_load(history + (size_t)b * LL + l);
            sum += item_emb[(size_t)it * EMB + e];
        }
        sum += __shfl_xor(sum, 16);
        sum += __shfl_xor(sum, 32);
        if (lane < EMB) s_ui[g][lane] = sum / (float)history_len[b];
        __syncthreads();

        int h = (t >> 4) & 3;
        int o = t & 15;
        float acc = 0.f;
#pragma unroll
        for (int ee = 0; ee < EMB; ++ee)
            acc += s_ui[g][ee] * s_wq[(h * EMB + ee) * OUTD + o];
        s_q[g][h * OUTD + o] = acc;
        __syncthreads();

        // q~_e = sum_o wk[h][e][o] * q_o
        float qt = 0.f;
#pragma unroll
        for (int oo = 0; oo < OUTD; ++oo)
            qt += s_wk[(h * EMB + o) * OUTD + oo] * s_q[g][h * OUTD + oo];
        qtbuf[((size_t)b * NH + h) * EMB + o] = (_Float16)qt;
    } else {
        // ---- Wkv[h][e][p] = sum_o wk[h][e][o] * wv[h][o][p] ----
        for (int i = t; i < NH * EMB * OUTD; i += 256) {
            int h = i >> 8, e = (i >> 4) & 15, p = i & 15;
            float a = 0.f;
#pragma unroll
            for (int o = 0; o < OUTD; ++o)
                a += wk[(h * EMB + e) * OUTD + o] * wv[(h * OUTD + o) * OUTD + p];
            Wkv[i] = a;
        }
    }
}

// ---------------------------------------------------------------------------
// Kernel 2 (fused attn + epilogue): grid BB/4, 256 threads, wave = head.
// Attn core is the R2-verified quad-cooperative gather (44.3 us measured;
// triple-confirmed request-rate floor: 6.55M random 32-B rows x ~4.1 cy/row/CU
// -- invariant to bytes/row, lanes/row, instr count), retargeted at the
// 1.6 MB shared u-table: 4 lanes x 8 B cover one 32-B row; 16 rows per vmem
// instr. Each wave loops over the block's 4 b's for its head.
// Epilogue: after one barrier, wave w runs the R1-verified per-b MLP for
// b_local = w, entirely wave-private (WAVE_SYNC between LDS stages).
// Kills the 2 MB gat round-trip and the third launch. LDS-stream design
// (R4-R6) refuted empirically: 82 us vs this structure's 44 us.
// ---------------------------------------------------------------------------
__global__ __launch_bounds__(256, 4) void attn_epi_kernel(
    const _Float16* __restrict__ tbl,
    const _Float16* __restrict__ qtbuf,
    const int*   __restrict__ sample_index,
    const float* __restrict__ Wkv,
    const float* __restrict__ item_emb,
    const float* __restrict__ w_out,
    const float* __restrict__ l1_w, const float* __restrict__ l1_b,
    const float* __restrict__ l2_w, const float* __restrict__ l2_b,
    const float* __restrict__ l3_w, const float* __restrict__ l3_b,
    const float* __restrict__ user_bias, const float* __restrict__ item_bias,
    const int*   __restrict__ x,
    float*       __restrict__ out)
{
    __shared__ float s_gat[4][NH * OUTD];
    __shared__ float s_ue[4][OUTD];
    __shared__ float s_ie[4][EMB];
    __shared__ float s_x1[4][HID];
    __shared__ float s_x2[4][HID / 2];

    int h    = threadIdx.x >> 6;    // wave = head
    int lane = threadIdx.x & 63;
    int g    = lane >> 2;           // row slot within a round (16 per round)
    int qt   = lane & 3;            // which 8-B quarter of the 32-B row

    const h4* U4 = (const h4*)tbl;

    for (int bl = 0; bl < 4; ++bl) {
        int b = blockIdx.x * 4 + bl;

        // coalesced preload of all 200 indices (nt: pure stream)
        const int* si = sample_index + ((size_t)h * BB + b) * SS;
        int pre0 = __builtin_nontemporal_load(si + lane);
        int pre1 = __builtin_nontemporal_load(si + lane + 64);
        int pre2 = __builtin_nontemporal_load(si + lane + 128);
        int pre3 = (lane < 8) ? __builtin_nontemporal_load(si + lane + 192) : 0;

        // this lane's quarter of q~ (fp16)
        h4 qh = ((const h4*)(qtbuf + ((size_t)b * NH + h) * EMB))[qt];
        h2 qlo = {qh.x, qh.y};
        h2 qhi = {qh.z, qh.w};

        // broadcast per-round row index to the owning quad
        int idx[13];
#pragma unroll
        for (int r = 0; r < 13; ++r) {
            int pre = (r < 4) ? pre0 : (r < 8) ? pre1 : (r < 12) ? pre2 : pre3;
            idx[r] = __shfl(pre, (r & 3) * 16 + g, 64);
        }

        // all 13 quad-cooperative gathers in flight (packed fp16, 26 VGPR)
        h4 kq[13];
#pragma unroll
        for (int r = 0; r < 13; ++r)
            kq[r] = U4[(size_t)idx[r] * 4 + qt];

        // single fused pass: quarter-dot, quad reduce, exp, accumulate
        float l = 0.f;
        v4f c = {0.f, 0.f, 0.f, 0.f};
#pragma unroll
        for (int r = 0; r < 13; ++r) {
            h2 klo = {kq[r].x, kq[r].y};
            h2 khi = {kq[r].z, kq[r].w};
            float p = __builtin_amdgcn_fdot2(klo, qlo,
                      __builtin_amdgcn_fdot2(khi, qhi, 0.f, false), false);
            p += __shfl_xor(p, 1);
            p += __shfl_xor(p, 2);
            float w = __expf(p);              // no-max softmax: |u.q~| ~ 1e-5
            if (r == 12) w = (g < 8) ? w : 0.f;  // round 12: s=192..207 mask
            l += w;
            c += w * __builtin_convertvector(kq[r], v4f);
        }
#pragma unroll
        for (int off = 4; off < 64; off <<= 1) {  // cross-group, qt-preserving
            l   += __shfl_xor(l, off);
            c.x += __shfl_xor(c.x, off);
            c.y += __shfl_xor(c.y, off);
            c.z += __shfl_xor(c.z, off);
            c.w += __shfl_xor(c.w, off);
        }
        float inv = 1.f / l;

        // gat[p=g] = sum_e cu[e] * Wkv[h][e][g] / l ; lane owns e = qt*4..+3
        float part = c.x * Wkv[((size_t)h * EMB + qt * 4 + 0) * OUTD + g]
                   + c.y * Wkv[((size_t)h * EMB + qt * 4 + 1) * OUTD + g]
                   + c.z * Wkv[((size_t)h * EMB + qt * 4 + 2) * OUTD + g]
                   + c.w * Wkv[((size_t)h * EMB + qt * 4 + 3) * OUTD + g];
        part += __shfl_xor(part, 1);
        part += __shfl_xor(part, 2);
        if (qt == 0)
            s_gat[bl][h * OUTD + g] = part * inv;
    }
    __syncthreads();   // s_gat complete for all 4 b's x 4 heads

    // ---- per-wave epilogue: wave h handles b_local = h (wave-private) ----
    int b   = blockIdx.x * 4 + h;
    int uid = x[(size_t)b * 2 + 0];
    int iid = x[(size_t)b * 2 + 1];

    if (lane < EMB) s_ie[h][lane] = item_emb[(size_t)iid * EMB + lane];
    if (lane < OUTD) {
        float acc = 0.f;
#pragma unroll
        for (int j = 0; j < NH * OUTD; ++j)
            acc += s_gat[h][j] * w_out[j * OUTD + lane];
        s_ue[h][lane] = acc;
    }
    WAVE_SYNC();

    if (lane < HID) {
        float acc = l1_b[lane];
#pragma unroll
        for (int i = 0; i < EMB; ++i) {
            float ue = s_ue[h][i], ie = s_ie[h][i];
            acc += ue * l1_w[i * HID + lane]
                 + ie * l1_w[(EMB + i) * HID + lane]
                 + ue * ie * l1_w[(2 * EMB + i) * HID + lane];
        }
        s_x1[h][lane] = tanhf(acc);
    }
    WAVE_SYNC();

    if (lane < HID / 2) {
        float acc = l2_b[lane];
#pragma unroll
        for (int j = 0; j < HID; ++j)
            acc += s_x1[h][j] * l2_w[j * (HID / 2) + lane];
        s_x2[h][lane] = tanhf(acc);
    }
    WAVE_SYNC();

    if (lane == 0) {
        float x3 = l3_b[0];
#pragma unroll
        for (int j = 0; j < HID / 2; ++j) x3 += s_x2[h][j] * l3_w[j];
        float ratings = 0.f;
#pragma unroll
        for (int o = 0; o < OUTD; ++o) ratings += s_ue[h][o] * s_ie[h][o];
        out[b] = 0.5f * (ratings + x3) + user_bias[uid] + item_bias[iid];
    }
}

// ---------------------------------------------------------------------------
extern "C" void kernel_launch(void* const* d_in, const int* in_sizes, int n_in,
                              void* d_out, int out_size, void* d_ws, size_t ws_size,
                              hipStream_t stream) {
    const float* user_embedding = (const float*)d_in[0];
    const float* item_embedding = (const float*)d_in[1];
    const float* wq             = (const float*)d_in[2];
    const float* wk             = (const float*)d_in[3];
    const float* wv             = (const float*)d_in[4];
    const float* w_out          = (const float*)d_in[5];
    const float* l1_w           = (const float*)d_in[6];
    const float* l1_b           = (const float*)d_in[7];
    const float* l2_w           = (const float*)d_in[8];
    const float* l2_b           = (const float*)d_in[9];
    const float* l3_w           = (const float*)d_in[10];
    const float* l3_b           = (const float*)d_in[11];
    const float* user_bias      = (const float*)d_in[12];
    const float* item_bias      = (const float*)d_in[13];
    const int*   x              = (const int*)d_in[14];
    const int*   history        = (const int*)d_in[15];
    const int*   history_len    = (const int*)d_in[16];
    const int*   supp_users     = (const int*)d_in[17];
    const int*   sample_index   = (const int*)d_in[18];
    float* out = (float*)d_out;

    char* ws = (char*)d_ws;
    _Float16* tbl = (_Float16*)ws;                       // 1.6 MB
    ws += (size_t)NSUPP * EMB * sizeof(_Float16);
    _Float16* qtbuf = (_Float16*)ws;                     // 1 MB
    ws += (size_t)BB * NH * EMB * sizeof(_Float16);
    float* Wkv = (float*)ws;                             // 4 KB

    prep_kernel<<<NSUPP / 16 + BB / 4 + 1, 256, 0, stream>>>(
        user_embedding, supp_users, wk, wq, wv,
        item_embedding, history, history_len, tbl, qtbuf, Wkv);
    attn_epi_kernel<<<BB / 4, 256, 0, stream>>>(
        tbl, qtbuf, sample_index, Wkv, item_embedding, w_out,
        l1_w, l1_b, l2_w, l2_b, l3_w, l3_b,
        user_bias, item_bias, x, out);
}